// Round 5
// baseline (396.597 us; speedup 1.0000x reference)
//
#include <hip/hip_runtime.h>
#include <cstdint>
#include <cstddef>

#define B_ 4
#define T_ 2048
#define C_ 768
#define H_ 12
#define D_ 64
#define M_ (B_*T_)      // 8192
#define C3_ 2304
#define HID_ 3072

typedef unsigned short ushort_t;
typedef __bf16 bf16x8_t __attribute__((ext_vector_type(8)));
typedef float f32x4 __attribute__((ext_vector_type(4)));

typedef const __attribute__((address_space(1))) void* gas_ptr;
typedef __attribute__((address_space(3))) void* las_ptr;

__device__ __forceinline__ void gload_lds16(const ushort_t* g, ushort_t* l) {
  // async global->LDS, 16B per lane; LDS dest = wave-uniform base + lane*16
  __builtin_amdgcn_global_load_lds((gas_ptr)g, (las_ptr)l, 16, 0, 0);
}

__device__ __forceinline__ float bf2f(ushort_t h) {
  union { unsigned int u; float f; } cv; cv.u = ((unsigned int)h) << 16; return cv.f;
}
__device__ __forceinline__ ushort_t f2bf(float f) {
  union { float f; unsigned int u; } cv; cv.f = f;
  unsigned int u = cv.u;
  unsigned int r = (u + 0x7FFFu + ((u >> 16) & 1u)) >> 16;
  return (ushort_t)r;
}
__device__ __forceinline__ ushort_t f2bf_trunc(float f) {   // RTZ: 1 op; fine for P in (0,1]
  union { float f; unsigned int u; } cv; cv.f = f;
  return (ushort_t)(cv.u >> 16);
}

// R13: branchless GELU. libm erff is branchy (~40+ VALU) and made the FC
// GEMM 45% VALUBusy. A&S 7.1.26 erf approx, |abs err| <= 1.5e-7 (invisible
// at bf16): rcp + exp2 + 5-FMA Horner, ~16 straight-line ops.
__device__ __forceinline__ float gelu_f(float v) {
  float z = fabsf(v) * 0.70710678118654752f;
  float t = __builtin_amdgcn_rcpf(fmaf(0.3275911f, z, 1.0f));
  float e = exp2f(z * z * -1.44269504088896340736f);
  float p = t * fmaf(t, fmaf(t, fmaf(t, fmaf(t, 1.061405429f, -1.453152027f),
                                     1.421413741f), -0.284496736f), 0.254829592f);
  float ea = fmaf(-p, e, 1.0f);            // erf(|z|), >= 0
  float er = copysignf(ea, v);
  return 0.5f * v * (1.0f + er);
}

// ---------------- transpose+cast W[K,N] f32 -> Wt[N,K] bf16 ----------------
__global__ __launch_bounds__(256) void transpose_k(const float* __restrict__ in,
                                                   ushort_t* __restrict__ out, int K, int N) {
  __shared__ ushort_t tile[32][33];
  int nx = threadIdx.x, ky = threadIdx.y;           // block (32,8)
  int n0 = blockIdx.x * 32, k0 = blockIdx.y * 32;
#pragma unroll
  for (int i = 0; i < 4; i++)
    tile[ky + i * 8][nx] = f2bf(in[(size_t)(k0 + ky + i * 8) * N + n0 + nx]);
  __syncthreads();
#pragma unroll
  for (int i = 0; i < 4; i++)
    out[(size_t)(n0 + ky + i * 8) * K + k0 + nx] = tile[nx][ky + i * 8];
}

// ---------------- V transpose: qkv V-part [t][d] -> Vg[bh][d][t] ----------------
__global__ __launch_bounds__(256) void vtrans_k(const ushort_t* __restrict__ qkv,
                                                ushort_t* __restrict__ vg) {
  __shared__ ushort_t tile[32][33];
  int nx = threadIdx.x, ky = threadIdx.y;           // block (32,8)
  int t0 = blockIdx.x * 32, d0 = blockIdx.y * 32;
  int bh = blockIdx.z;
  int b = bh / H_, h = bh % H_;
  const ushort_t* src = qkv + (size_t)b * T_ * C3_ + 2 * C_ + h * D_;
#pragma unroll
  for (int i = 0; i < 4; i++)
    tile[ky + i * 8][nx] = src[(size_t)(t0 + ky + i * 8) * C3_ + d0 + nx];
  __syncthreads();
  ushort_t* dst = vg + (size_t)bh * D_ * T_;
#pragma unroll
  for (int i = 0; i < 4; i++)
    dst[(size_t)(d0 + ky + i * 8) * T_ + t0 + nx] = tile[nx][ky + i * 8];
}

// ---------------- layernorm (row = 768), f32 in -> bf16 out ----------------
__global__ __launch_bounds__(256) void ln_k(const float* __restrict__ x, const float* __restrict__ g,
                                            const float* __restrict__ bb, ushort_t* __restrict__ out) {
  __shared__ float red[8];
  int row = blockIdx.x, t = threadIdx.x;
  const float* xr = x + (size_t)row * C_;
  float v0 = xr[t], v1 = xr[t + 256], v2 = xr[t + 512];
  float s = v0 + v1 + v2;
  float s2 = v0 * v0 + v1 * v1 + v2 * v2;
#pragma unroll
  for (int m = 32; m >= 1; m >>= 1) { s += __shfl_xor(s, m); s2 += __shfl_xor(s2, m); }
  int w = t >> 6;
  if ((t & 63) == 0) { red[w * 2] = s; red[w * 2 + 1] = s2; }
  __syncthreads();
  s = red[0] + red[2] + red[4] + red[6];
  s2 = red[1] + red[3] + red[5] + red[7];
  float mu = s * (1.f / C_);
  float var = s2 * (1.f / C_) - mu * mu;
  float rstd = rsqrtf(var + 1e-5f);
  out[(size_t)row * C_ + t]       = f2bf((v0 - mu) * rstd * g[t] + bb[t]);
  out[(size_t)row * C_ + t + 256] = f2bf((v1 - mu) * rstd * g[t + 256] + bb[t + 256]);
  out[(size_t)row * C_ + t + 512] = f2bf((v2 - mu) * rstd * g[t + 512] + bb[t + 512]);
}

// ---------------- GEMM: C[M,N] = A[M,K] @ Bt[N,K]^T, fused epilogues ----------------
// R10: pipelined K-loop + bijective XCD swizzle. R11: LDS bank swizzle
// (conflicts 4.7M -> 0). R12: depth-2 prefetch (null -- latency depth was not
// the limiter, matches m196). R13: ONE barrier per K-step via 4-deep circular
// buffers (was 2 barriers + 2 waitcnt per step; m233 says this class is the
// dominant 2-phase overhead). Per sub-step: {vmcnt(N); barrier; STAGE(t+3);
// COMPUTE(t)}. Stage-after-barrier is overwrite-safe (all waves' COMPUTE of
// that buffer precedes the barrier in program order); stage-before-MFMA
// issues loads early. vmcnt steady 8; exact tail counts 8/8/4/0 in the last
// iteration (tile t needs stages >t in flight only). K/32 % 4 == 0 for
// K in {768, 3072}. LDS 64KB -> 2 blocks/CU.
#define MFMA16(d, a, b) d = __builtin_amdgcn_mfma_f32_16x16x32_bf16(a, b, d, 0, 0, 0)

template <int EPI>
__global__ void gemm_bt_k(const ushort_t* __restrict__ A,
                          const ushort_t* __restrict__ Bt,
                          const float* __restrict__ res,
                          void* __restrict__ outp,
                          int N, int K) {
  __shared__ __align__(16) ushort_t As[4][128][32];
  __shared__ __align__(16) ushort_t Bs[4][128][32];
  int t = threadIdx.x;

  // XCD-aware block swizzle (all launch grids are %8==0; guard anyway)
  int nwg = (int)(gridDim.x * gridDim.y);
  int orig = (int)(blockIdx.y * gridDim.x + blockIdx.x);
  int swz = (nwg & 7) ? orig : ((orig & 7) * (nwg >> 3) + (orig >> 3));
  int bx = swz % (int)gridDim.x, by = swz / (int)gridDim.x;
  int bn = bx * 128, bm = by * 128;

  int lane = t & 63, w = t >> 6;
  int wm = (w >> 1) * 64, wn = (w & 1) * 64;
  int lm = lane & 15;

  // staging: lane -> (row lr, phys chunk lane&3); source = logical chunk
  // (lane&3) ^ ((lr>>1)&3)  [lr>>1 == lane>>3]
  int lr = lane >> 2;
  int lc = (((lane & 3) ^ ((lane >> 3) & 3)) * 8);
  // read side: phys chunk = q ^ ((lm>>1)&3); lane bits 1-2 == lm bits 1-2
  int cx = (((lane >> 4) ^ ((lane >> 1) & 3)) * 8);

  const ushort_t* ga0 = A  + (size_t)(bm + w * 16 + lr) * K + lc;
  const ushort_t* gb0 = Bt + (size_t)(bn + w * 16 + lr) * K + lc;
  const size_t kstep64 = (size_t)64 * K;

  const f32x4 fz = {0.f, 0.f, 0.f, 0.f};
  f32x4 acc00 = fz, acc01 = fz, acc02 = fz, acc03 = fz;
  f32x4 acc10 = fz, acc11 = fz, acc12 = fz, acc13 = fz;
  f32x4 acc20 = fz, acc21 = fz, acc22 = fz, acc23 = fz;
  f32x4 acc30 = fz, acc31 = fz, acc32 = fz, acc33 = fz;

#define STAGE(BUF, TILE) do {                                   \
    int ko_ = (TILE) * 32;                                      \
    gload_lds16(ga0 + ko_, &As[BUF][w * 16][0]);                \
    gload_lds16(ga0 + kstep64 + ko_, &As[BUF][w * 16 + 64][0]); \
    gload_lds16(gb0 + ko_, &Bs[BUF][w * 16][0]);                \
    gload_lds16(gb0 + kstep64 + ko_, &Bs[BUF][w * 16 + 64][0]); \
  } while (0)

#define COMPUTE(BUF) do {                                            \
    bf16x8_t af0 = *(const bf16x8_t*)&As[BUF][wm + lm][cx];          \
    bf16x8_t af1 = *(const bf16x8_t*)&As[BUF][wm + 16 + lm][cx];     \
    bf16x8_t af2 = *(const bf16x8_t*)&As[BUF][wm + 32 + lm][cx];     \
    bf16x8_t af3 = *(const bf16x8_t*)&As[BUF][wm + 48 + lm][cx];     \
    bf16x8_t bg0 = *(const bf16x8_t*)&Bs[BUF][wn + lm][cx];          \
    bf16x8_t bg1 = *(const bf16x8_t*)&Bs[BUF][wn + 16 + lm][cx];     \
    bf16x8_t bg2 = *(const bf16x8_t*)&Bs[BUF][wn + 32 + lm][cx];     \
    bf16x8_t bg3 = *(const bf16x8_t*)&Bs[BUF][wn + 48 + lm][cx];     \
    MFMA16(acc00, af0, bg0); MFMA16(acc01, af0, bg1); MFMA16(acc02, af0, bg2); MFMA16(acc03, af0, bg3); \
    MFMA16(acc10, af1, bg0); MFMA16(acc11, af1, bg1); MFMA16(acc12, af1, bg2); MFMA16(acc13, af1, bg3); \
    MFMA16(acc20, af2, bg0); MFMA16(acc21, af2, bg1); MFMA16(acc22, af2, bg2); MFMA16(acc23, af2, bg3); \
    MFMA16(acc30, af3, bg0); MFMA16(acc31, af3, bg1); MFMA16(acc32, af3, bg2); MFMA16(acc33, af3, bg3); \
  } while (0)

#define FENCE asm volatile("" ::: "memory")

  int nsteps = K >> 5;                 // K/32: 24 (K=768) or 96 (K=3072), %4==0
  STAGE(0, 0);
  STAGE(1, 1);
  STAGE(2, 2);
  for (int s = 0; s < nsteps; s += 4) {
    // sub a: tile s (buf0); stage tile s+3 -> buf3 (always valid: s+3 <= nsteps-1)
    asm volatile("s_waitcnt vmcnt(8)" ::: "memory");   // tile s landed
    __builtin_amdgcn_s_barrier();
    FENCE;
    STAGE(3, s + 3);
    COMPUTE(0);
    FENCE;
    // sub b: tile s+1 (buf1); stage tile s+4 -> buf0
    asm volatile("s_waitcnt vmcnt(8)" ::: "memory");   // tile s+1 landed (s+2,s+3 fly)
    __builtin_amdgcn_s_barrier();
    FENCE;
    if (s + 4 < nsteps) STAGE(0, s + 4);
    COMPUTE(1);
    FENCE;
    // sub c: tile s+2 (buf2); stage tile s+5 -> buf1
    if (s + 4 < nsteps) { asm volatile("s_waitcnt vmcnt(8)" ::: "memory"); }
    else                { asm volatile("s_waitcnt vmcnt(4)" ::: "memory"); }  // only s+3 flies
    __builtin_amdgcn_s_barrier();
    FENCE;
    if (s + 5 < nsteps) STAGE(1, s + 5);
    COMPUTE(2);
    FENCE;
    // sub d: tile s+3 (buf3); stage tile s+6 -> buf2
    if (s + 4 < nsteps) { asm volatile("s_waitcnt vmcnt(8)" ::: "memory"); }
    else                { asm volatile("s_waitcnt vmcnt(0)" ::: "memory"); }  // drain
    __builtin_amdgcn_s_barrier();
    FENCE;
    if (s + 6 < nsteps) STAGE(2, s + 6);
    COMPUTE(3);
    FENCE;
  }
#undef FENCE
#undef STAGE
#undef COMPUTE

  int rowb = bm + wm + (lane >> 4) * 4;
  int colb = bn + wn + lm;

#define ST(vv, row, jj) do { \
    float v = (vv); \
    size_t idx = (size_t)(row) * N + colb + (jj) * 16; \
    if constexpr (EPI == 0) { ((ushort_t*)outp)[idx] = f2bf(v); } \
    else if constexpr (EPI == 1) { ((float*)outp)[idx] = v + res[idx]; } \
    else { ((ushort_t*)outp)[idx] = f2bf(gelu_f(v)); } \
  } while (0)
#define STROW(a0, a1, a2, a3, row, rr) \
    ST(a0[rr], row, 0); ST(a1[rr], row, 1); ST(a2[rr], row, 2); ST(a3[rr], row, 3);
#define STBLK(a0, a1, a2, a3, rbase) \
    STROW(a0, a1, a2, a3, (rbase), 0) STROW(a0, a1, a2, a3, (rbase) + 1, 1) \
    STROW(a0, a1, a2, a3, (rbase) + 2, 2) STROW(a0, a1, a2, a3, (rbase) + 3, 3)

  STBLK(acc00, acc01, acc02, acc03, rowb)
  STBLK(acc10, acc11, acc12, acc13, rowb + 16)
  STBLK(acc20, acc21, acc22, acc23, rowb + 32)
  STBLK(acc30, acc31, acc32, acc33, rowb + 48)
#undef ST
#undef STROW
#undef STBLK
}

// ---------------- flash attention (causal) ----------------
// R9: cooperative LDS staging of K/V tiles (all 4 waves share the same tiles).
// Double-buffered global_load_lds with counted s_waitcnt vmcnt(4) + raw
// s_barrier so the next tile's loads stay in flight across the barrier.
// XOR-swizzle applied on BOTH sides (pre-swizzled global source + swizzled
// ds_read). LDS 41KB -> 3 blocks/CU.
__device__ __forceinline__ void stage64(const ushort_t* __restrict__ g, size_t strideE,
                                        ushort_t* l, int w, int lane) {
  // stage 16 rows (w*16..w*16+15) of a 64x64 bf16 tile: 2 x 1KB gload_lds
  int rl = lane >> 3;                        // local row 0..7 within 8-row slab
  int ce = ((lane & 7) ^ rl) << 3;           // pre-swizzled element col (8-elem chunks)
  const ushort_t* g0 = g + (size_t)(w * 16 + rl) * strideE + ce;
  gload_lds16(g0, l + (size_t)(w * 16) * 64);
  const ushort_t* g1 = g + (size_t)(w * 16 + 8 + rl) * strideE + ce;
  gload_lds16(g1, l + (size_t)(w * 16 + 8) * 64);
}

__global__ __launch_bounds__(256, 3) void attn_k(const ushort_t* __restrict__ qkv,
                                                 const ushort_t* __restrict__ vg,
                                                 ushort_t* __restrict__ y) {
  __shared__ __align__(16) ushort_t Ks[2][64][64];   // [buf][t_local][d] swizzled
  __shared__ __align__(16) ushort_t Vs[2][64][64];   // [buf][d][t_local] swizzled
  __shared__ __align__(16) ushort_t Ps[4][16][72];

  int t = threadIdx.x;
  int w = t >> 6, lane = t & 63;
  int lm = lane & 15, qq = lane >> 4, q8 = qq * 8;
  int bh = blockIdx.x;
  int qt = (int)gridDim.y - 1 - (int)blockIdx.y;   // heavy q-tiles dispatch first
  int b = bh / H_, h = bh % H_;

  size_t baserow = (size_t)b * T_;
  const ushort_t* qkvb = qkv + baserow * C3_ + h * D_;
  const ushort_t* kbase = qkvb + C_;
  const ushort_t* vbase = vg + (size_t)bh * D_ * T_;

  int qrow0 = qt * 64 + w * 16;   // this wave's 16 q rows
  const ushort_t* qp = qkvb + (size_t)(qrow0 + lm) * C3_ + q8;
  bf16x8_t aq0 = *(const bf16x8_t*)(qp);
  bf16x8_t aq1 = *(const bf16x8_t*)(qp + 32);
  __builtin_amdgcn_s_waitcnt(0);   // drain Q loads so in-loop vmcnt counting is exact

  const f32x4 fz = {0.f, 0.f, 0.f, 0.f};
  f32x4 aO0 = fz, aO1 = fz, aO2 = fz, aO3 = fz;
  f32x4 lsum = fz;                 // per-lane partial softmax denominators

  const float SC = 0.125f * 1.44269504088896340736f;  // scale * log2(e)

#define BODY(CUR, KT, MASKED)                                                   \
  {                                                                             \
    const char* Kb = (const char*)&Ks[CUR][0][0];                               \
    const char* Vb = (const char*)&Vs[CUR][0][0];                               \
    const int rsw = (lm & 7) << 4;                                              \
    const int c0 = (qq * 16) ^ rsw;                                             \
    const int c1 = (64 + qq * 16) ^ rsw;                                        \
    bf16x8_t kf[8], vv[8];                                                      \
    _Pragma("unroll") for (int j = 0; j < 4; j++) {                             \
      int rb = (j * 16 + lm) << 7;                                              \
      kf[2*j]   = *(const bf16x8_t*)(Kb + rb + c0);                             \
      kf[2*j+1] = *(const bf16x8_t*)(Kb + rb + c1);                             \
      vv[2*j]   = *(const bf16x8_t*)(Vb + rb + c0);                             \
      vv[2*j+1] = *(const bf16x8_t*)(Vb + rb + c1);                             \
    }                                                                           \
    f32x4 sa0 = fz, sa1 = fz, sa2 = fz, sa3 = fz;                               \
    MFMA16(sa0, aq0, kf[0]); MFMA16(sa0, aq1, kf[1]);                           \
    MFMA16(sa1, aq0, kf[2]); MFMA16(sa1, aq1, kf[3]);                           \
    MFMA16(sa2, aq0, kf[4]); MFMA16(sa2, aq1, kf[5]);                           \
    MFMA16(sa3, aq0, kf[6]); MFMA16(sa3, aq1, kf[7]);                           \
    _Pragma("unroll") for (int j = 0; j < 4; j++) {                             \
      f32x4 sj = (j == 0) ? sa0 : (j == 1) ? sa1 : (j == 2) ? sa2 : sa3;        \
      _Pragma("unroll") for (int r2 = 0; r2 < 4; r2++) {                        \
        float v = sj[r2] * SC;                                                  \
        if (MASKED && (j * 16 + lm) > (w * 16 + qq * 4 + r2)) v = -1e30f;       \
        float p = exp2f(v);                                                     \
        lsum[r2] += p;                                                          \
        Ps[w][qq * 4 + r2][j * 16 + lm] = f2bf_trunc(p);                        \
      }                                                                         \
    }                                                                           \
    {                                                                           \
      bf16x8_t ap_lo = *(const bf16x8_t*)&Ps[w][lm][q8];                        \
      bf16x8_t ap_hi = *(const bf16x8_t*)&Ps[w][lm][32 + q8];                   \
      MFMA16(aO0, ap_lo, vv[0]); MFMA16(aO0, ap_hi, vv[1]);                     \
      MFMA16(aO1, ap_lo, vv[2]); MFMA16(aO1, ap_hi, vv[3]);                     \
      MFMA16(aO2, ap_lo, vv[4]); MFMA16(aO2, ap_hi, vv[5]);                     \
      MFMA16(aO3, ap_lo, vv[6]); MFMA16(aO3, ap_hi, vv[7]);                     \
    }                                                                           \
  }

  // prologue: stage tile 0 into buffer 0 (4 async loads per wave)
  stage64(kbase, C3_, &Ks[0][0][0], w, lane);
  stage64(vbase, T_, &Vs[0][0][0], w, lane);
  int cur = 0;
  for (int kt = 0; kt <= qt; ++kt) {
    if (kt < qt) {
      // issue next tile's loads into the other buffer, keep them in flight
      stage64(kbase + (size_t)(kt + 1) * 64 * C3_, C3_, &Ks[cur ^ 1][0][0], w, lane);
      stage64(vbase + (size_t)(kt + 1) * 64,       T_,  &Vs[cur ^ 1][0][0], w, lane);
      asm volatile("s_waitcnt vmcnt(4)" ::: "memory");  // tile kt landed; kt+1 in flight
    } else {
      asm volatile("s_waitcnt vmcnt(0)" ::: "memory");  // last tile: drain
    }
    __builtin_amdgcn_s_barrier();      // all waves' tile-kt data visible
    asm volatile("" ::: "memory");     // fence: no LDS reads hoisted above barrier
    if (kt == qt) { BODY(cur, kt, true) }
    else          { BODY(cur, kt, false) }
    asm volatile("" ::: "memory");     // fence: reads done before buffer reuse
    __builtin_amdgcn_s_barrier();      // safe to overwrite buffer cur next iter
    cur ^= 1;
  }
#undef BODY

#pragma unroll
  for (int r2 = 0; r2 < 4; r2++) {
    float s = lsum[r2];
    s += __shfl_xor(s, 1);
    s += __shfl_xor(s, 2);
    s += __shfl_xor(s, 4);
    s += __shfl_xor(s, 8);
    float inv = 1.f / s;
    size_t orow = (baserow + qrow0 + qq * 4 + r2) * C_ + h * D_;
    y[orow + lm]      = f2bf(aO0[r2] * inv);
    y[orow + 16 + lm] = f2bf(aO1[r2] * inv);
    y[orow + 32 + lm] = f2bf(aO2[r2] * inv);
    y[orow + 48 + lm] = f2bf(aO3[r2] * inv);
  }
}

extern "C" void kernel_launch(void* const* d_in, const int* in_sizes, int n_in,
                              void* d_out, int out_size, void* d_ws, size_t ws_size,
                              hipStream_t stream) {
  (void)in_sizes; (void)n_in; (void)out_size; (void)ws_size;
  const float* x      = (const float*)d_in[0];
  const float* ln1_g  = (const float*)d_in[1];
  const float* ln1_b  = (const float*)d_in[2];
  const float* W_attn = (const float*)d_in[3];
  const float* W_o    = (const float*)d_in[4];
  const float* ln2_g  = (const float*)d_in[5];
  const float* ln2_b  = (const float*)d_in[6];
  const float* W_fc   = (const float*)d_in[7];
  const float* W_proj = (const float*)d_in[8];

  char* ws = (char*)d_ws;
  ushort_t* big  = (ushort_t*)(ws);
  ushort_t* Vg   = (ushort_t*)(ws + 37748736);  // V^T [48][64][2048] bf16; dead before h is written
  ushort_t* tmp  = (ushort_t*)(ws + 50331648);  // xhat1 / y / xhat2 (8192x768 bf16)
  float*    x2   = (float*)   (ws + 62914560);  // residual1 fp32 (8192x768)
  ushort_t* Wat  = (ushort_t*)(ws + 88080384);  // W_attn^T [2304,768] bf16
  ushort_t* Wot  = (ushort_t*)(ws + 91619328);  // W_o^T    [768,768]  bf16
  ushort_t* Wfct = (ushort_t*)(ws + 92798976);  // W_fc^T   [3072,768] bf16
  ushort_t* Wpt  = (ushort_t*)(ws + 97517568);  // W_proj^T [768,3072] bf16

  dim3 tb(32, 8);
  transpose_k<<<dim3(C3_ / 32, C_ / 32), tb, 0, stream>>>(W_attn, Wat, C_, C3_);
  transpose_k<<<dim3(C_ / 32, C_ / 32), tb, 0, stream>>>(W_o, Wot, C_, C_);
  transpose_k<<<dim3(HID_ / 32, C_ / 32), tb, 0, stream>>>(W_fc, Wfct, C_, HID_);
  transpose_k<<<dim3(C_ / 32, HID_ / 32), tb, 0, stream>>>(W_proj, Wpt, HID_, C_);

  ln_k<<<M_, 256, 0, stream>>>(x, ln1_g, ln1_b, tmp);
  gemm_bt_k<0><<<dim3(C3_ / 128, M_ / 128), 256, 0, stream>>>(tmp, Wat, nullptr, big, C3_, C_);
  vtrans_k<<<dim3(T_ / 32, D_ / 32, B_ * H_), tb, 0, stream>>>(big, Vg);
  attn_k<<<dim3(B_ * H_, T_ / 64), 256, 0, stream>>>(big, Vg, tmp);
  gemm_bt_k<1><<<dim3(C_ / 128, M_ / 128), 256, 0, stream>>>(tmp, Wot, x, x2, C_, C_);
  ln_k<<<M_, 256, 0, stream>>>(x2, ln2_g, ln2_b, tmp);
  gemm_bt_k<2><<<dim3(HID_ / 128, M_ / 128), 256, 0, stream>>>(tmp, Wfct, nullptr, big, HID_, C_);
  gemm_bt_k<1><<<dim3(C_ / 128, M_ / 128), 256, 0, stream>>>(big, Wpt, x2, d_out, C_, HID_);
}

// Round 6
// 380.382 us; speedup vs baseline: 1.0426x; 1.0426x over previous
//
#include <hip/hip_runtime.h>
#include <cstdint>
#include <cstddef>

#define B_ 4
#define T_ 2048
#define C_ 768
#define H_ 12
#define D_ 64
#define M_ (B_*T_)      // 8192
#define C3_ 2304
#define HID_ 3072

typedef unsigned short ushort_t;
typedef __bf16 bf16x8_t __attribute__((ext_vector_type(8)));
typedef float f32x4 __attribute__((ext_vector_type(4)));

typedef const __attribute__((address_space(1))) void* gas_ptr;
typedef __attribute__((address_space(3))) void* las_ptr;

__device__ __forceinline__ void gload_lds16(const ushort_t* g, ushort_t* l) {
  // async global->LDS, 16B per lane; LDS dest = wave-uniform base + lane*16
  __builtin_amdgcn_global_load_lds((gas_ptr)g, (las_ptr)l, 16, 0, 0);
}

__device__ __forceinline__ float bf2f(ushort_t h) {
  union { unsigned int u; float f; } cv; cv.u = ((unsigned int)h) << 16; return cv.f;
}
__device__ __forceinline__ ushort_t f2bf(float f) {
  union { float f; unsigned int u; } cv; cv.f = f;
  unsigned int u = cv.u;
  unsigned int r = (u + 0x7FFFu + ((u >> 16) & 1u)) >> 16;
  return (ushort_t)r;
}
__device__ __forceinline__ ushort_t f2bf_trunc(float f) {   // RTZ: 1 op; fine for P in (0,1]
  union { float f; unsigned int u; } cv; cv.f = f;
  return (ushort_t)(cv.u >> 16);
}

// R13: branchless GELU (A&S 7.1.26, |err|<=1.5e-7; erff was 45% VALUBusy).
__device__ __forceinline__ float gelu_f(float v) {
  float z = fabsf(v) * 0.70710678118654752f;
  float t = __builtin_amdgcn_rcpf(fmaf(0.3275911f, z, 1.0f));
  float e = exp2f(z * z * -1.44269504088896340736f);
  float p = t * fmaf(t, fmaf(t, fmaf(t, fmaf(t, 1.061405429f, -1.453152027f),
                                     1.421413741f), -0.284496736f), 0.254829592f);
  float ea = fmaf(-p, e, 1.0f);            // erf(|z|), >= 0
  float er = copysignf(ea, v);
  return 0.5f * v * (1.0f + er);
}

// ---------------- transpose+cast W[K,N] f32 -> Wt[N,K] bf16 ----------------
__global__ __launch_bounds__(256) void transpose_k(const float* __restrict__ in,
                                                   ushort_t* __restrict__ out, int K, int N) {
  __shared__ ushort_t tile[32][33];
  int nx = threadIdx.x, ky = threadIdx.y;           // block (32,8)
  int n0 = blockIdx.x * 32, k0 = blockIdx.y * 32;
#pragma unroll
  for (int i = 0; i < 4; i++)
    tile[ky + i * 8][nx] = f2bf(in[(size_t)(k0 + ky + i * 8) * N + n0 + nx]);
  __syncthreads();
#pragma unroll
  for (int i = 0; i < 4; i++)
    out[(size_t)(n0 + ky + i * 8) * K + k0 + nx] = tile[nx][ky + i * 8];
}

// ---------------- V transpose: qkv V-part [t][d] -> Vg[bh][d][t] ----------------
__global__ __launch_bounds__(256) void vtrans_k(const ushort_t* __restrict__ qkv,
                                                ushort_t* __restrict__ vg) {
  __shared__ ushort_t tile[32][33];
  int nx = threadIdx.x, ky = threadIdx.y;           // block (32,8)
  int t0 = blockIdx.x * 32, d0 = blockIdx.y * 32;
  int bh = blockIdx.z;
  int b = bh / H_, h = bh % H_;
  const ushort_t* src = qkv + (size_t)b * T_ * C3_ + 2 * C_ + h * D_;
#pragma unroll
  for (int i = 0; i < 4; i++)
    tile[ky + i * 8][nx] = src[(size_t)(t0 + ky + i * 8) * C3_ + d0 + nx];
  __syncthreads();
  ushort_t* dst = vg + (size_t)bh * D_ * T_;
#pragma unroll
  for (int i = 0; i < 4; i++)
    dst[(size_t)(d0 + ky + i * 8) * T_ + t0 + nx] = tile[nx][ky + i * 8];
}

// ---------------- layernorm (row = 768), f32 in -> bf16 out ----------------
__global__ __launch_bounds__(256) void ln_k(const float* __restrict__ x, const float* __restrict__ g,
                                            const float* __restrict__ bb, ushort_t* __restrict__ out) {
  __shared__ float red[8];
  int row = blockIdx.x, t = threadIdx.x;
  const float* xr = x + (size_t)row * C_;
  float v0 = xr[t], v1 = xr[t + 256], v2 = xr[t + 512];
  float s = v0 + v1 + v2;
  float s2 = v0 * v0 + v1 * v1 + v2 * v2;
#pragma unroll
  for (int m = 32; m >= 1; m >>= 1) { s += __shfl_xor(s, m); s2 += __shfl_xor(s2, m); }
  int w = t >> 6;
  if ((t & 63) == 0) { red[w * 2] = s; red[w * 2 + 1] = s2; }
  __syncthreads();
  s = red[0] + red[2] + red[4] + red[6];
  s2 = red[1] + red[3] + red[5] + red[7];
  float mu = s * (1.f / C_);
  float var = s2 * (1.f / C_) - mu * mu;
  float rstd = rsqrtf(var + 1e-5f);
  out[(size_t)row * C_ + t]       = f2bf((v0 - mu) * rstd * g[t] + bb[t]);
  out[(size_t)row * C_ + t + 256] = f2bf((v1 - mu) * rstd * g[t + 256] + bb[t + 256]);
  out[(size_t)row * C_ + t + 512] = f2bf((v2 - mu) * rstd * g[t + 512] + bb[t + 512]);
}

// ---------------- 128x128 GEMM (R11 structure, reverted from R13) ----------------
// R14: reverted 4-buffer/1-barrier experiment (regressed: 64KB LDS cut
// occupancy 28.7->19%, FETCH 43->65MB). Back to 2-buffer 32KB, vmcnt(4),
// 2 barriers/K-step, bank swizzle (conflicts 0), XCD swizzle, poly gelu.
#define MFMA16(d, a, b) d = __builtin_amdgcn_mfma_f32_16x16x32_bf16(a, b, d, 0, 0, 0)

template <int EPI>
__global__ void gemm_bt_k(const ushort_t* __restrict__ A,
                          const ushort_t* __restrict__ Bt,
                          const float* __restrict__ res,
                          void* __restrict__ outp,
                          int N, int K) {
  __shared__ __align__(16) ushort_t As[2][128][32];
  __shared__ __align__(16) ushort_t Bs[2][128][32];
  int t = threadIdx.x;

  int nwg = (int)(gridDim.x * gridDim.y);
  int orig = (int)(blockIdx.y * gridDim.x + blockIdx.x);
  int swz = (nwg & 7) ? orig : ((orig & 7) * (nwg >> 3) + (orig >> 3));
  int bx = swz % (int)gridDim.x, by = swz / (int)gridDim.x;
  int bn = bx * 128, bm = by * 128;

  int lane = t & 63, w = t >> 6;
  int wm = (w >> 1) * 64, wn = (w & 1) * 64;
  int lm = lane & 15;

  int lr = lane >> 2;
  int lc = (((lane & 3) ^ ((lane >> 3) & 3)) * 8);
  int cx = (((lane >> 4) ^ ((lane >> 1) & 3)) * 8);

  const ushort_t* ga0 = A  + (size_t)(bm + w * 16 + lr) * K + lc;
  const ushort_t* gb0 = Bt + (size_t)(bn + w * 16 + lr) * K + lc;
  const size_t kstep64 = (size_t)64 * K;

  const f32x4 fz = {0.f, 0.f, 0.f, 0.f};
  f32x4 acc00 = fz, acc01 = fz, acc02 = fz, acc03 = fz;
  f32x4 acc10 = fz, acc11 = fz, acc12 = fz, acc13 = fz;
  f32x4 acc20 = fz, acc21 = fz, acc22 = fz, acc23 = fz;
  f32x4 acc30 = fz, acc31 = fz, acc32 = fz, acc33 = fz;

#define STAGE(BUF, KOFF) do {                                   \
    gload_lds16(ga0 + (KOFF), &As[BUF][w * 16][0]);             \
    gload_lds16(ga0 + kstep64 + (KOFF), &As[BUF][w * 16 + 64][0]); \
    gload_lds16(gb0 + (KOFF), &Bs[BUF][w * 16][0]);             \
    gload_lds16(gb0 + kstep64 + (KOFF), &Bs[BUF][w * 16 + 64][0]); \
  } while (0)

#define COMPUTE(BUF) do {                                            \
    bf16x8_t af0 = *(const bf16x8_t*)&As[BUF][wm + lm][cx];          \
    bf16x8_t af1 = *(const bf16x8_t*)&As[BUF][wm + 16 + lm][cx];     \
    bf16x8_t af2 = *(const bf16x8_t*)&As[BUF][wm + 32 + lm][cx];     \
    bf16x8_t af3 = *(const bf16x8_t*)&As[BUF][wm + 48 + lm][cx];     \
    bf16x8_t bg0 = *(const bf16x8_t*)&Bs[BUF][wn + lm][cx];          \
    bf16x8_t bg1 = *(const bf16x8_t*)&Bs[BUF][wn + 16 + lm][cx];     \
    bf16x8_t bg2 = *(const bf16x8_t*)&Bs[BUF][wn + 32 + lm][cx];     \
    bf16x8_t bg3 = *(const bf16x8_t*)&Bs[BUF][wn + 48 + lm][cx];     \
    MFMA16(acc00, af0, bg0); MFMA16(acc01, af0, bg1); MFMA16(acc02, af0, bg2); MFMA16(acc03, af0, bg3); \
    MFMA16(acc10, af1, bg0); MFMA16(acc11, af1, bg1); MFMA16(acc12, af1, bg2); MFMA16(acc13, af1, bg3); \
    MFMA16(acc20, af2, bg0); MFMA16(acc21, af2, bg1); MFMA16(acc22, af2, bg2); MFMA16(acc23, af2, bg3); \
    MFMA16(acc30, af3, bg0); MFMA16(acc31, af3, bg1); MFMA16(acc32, af3, bg2); MFMA16(acc33, af3, bg3); \
  } while (0)

  STAGE(0, 0);
  for (int k0 = 0; k0 < K; k0 += 64) {           // K % 64 == 0 for all shapes
    STAGE(1, k0 + 32);
    asm volatile("s_waitcnt vmcnt(4)" ::: "memory");  // buf0 landed; buf1 in flight
    __builtin_amdgcn_s_barrier();
    asm volatile("" ::: "memory");
    COMPUTE(0);
    asm volatile("" ::: "memory");
    __builtin_amdgcn_s_barrier();                // buf0 reads done -> refillable
    if (k0 + 64 < K) {
      STAGE(0, k0 + 64);
      asm volatile("s_waitcnt vmcnt(4)" ::: "memory");  // buf1 landed; buf0 in flight
    } else {
      asm volatile("s_waitcnt vmcnt(0)" ::: "memory");  // tail: drain
    }
    __builtin_amdgcn_s_barrier();
    asm volatile("" ::: "memory");
    COMPUTE(1);
    asm volatile("" ::: "memory");
    __builtin_amdgcn_s_barrier();                // buf1 reads done -> refillable
  }
#undef STAGE
#undef COMPUTE

  int rowb = bm + wm + (lane >> 4) * 4;
  int colb = bn + wn + lm;

#define ST(vv, row, jj) do { \
    float v = (vv); \
    size_t idx = (size_t)(row) * N + colb + (jj) * 16; \
    if constexpr (EPI == 0) { ((ushort_t*)outp)[idx] = f2bf(v); } \
    else if constexpr (EPI == 1) { ((float*)outp)[idx] = v + res[idx]; } \
    else { ((ushort_t*)outp)[idx] = f2bf(gelu_f(v)); } \
  } while (0)
#define STROW(a0, a1, a2, a3, row, rr) \
    ST(a0[rr], row, 0); ST(a1[rr], row, 1); ST(a2[rr], row, 2); ST(a3[rr], row, 3);
#define STBLK(a0, a1, a2, a3, rbase) \
    STROW(a0, a1, a2, a3, (rbase), 0) STROW(a0, a1, a2, a3, (rbase) + 1, 1) \
    STROW(a0, a1, a2, a3, (rbase) + 2, 2) STROW(a0, a1, a2, a3, (rbase) + 3, 3)

  STBLK(acc00, acc01, acc02, acc03, rowb)
  STBLK(acc10, acc11, acc12, acc13, rowb + 16)
  STBLK(acc20, acc21, acc22, acc23, rowb + 32)
  STBLK(acc30, acc31, acc32, acc33, rowb + 48)
#undef ST
#undef STROW
#undef STBLK
}

// ---------------- 256x256 GEMM (R14, FC only) ----------------
// m230/m248 regime: 256-tile + 8 waves gives 64 MFMA per {vmcnt + 2 barriers}
// = 4x sync amortization over the 128-tile (whose 2-phase ceiling pinned
// MfmaUtil at 20% across R10-R13). BK=64, 2-deep dbuf (128KB LDS, 1 blk/CU),
// 8 gload_lds/wave/K-tile (wave w stages rows [w*32,w*32+32) of A and B),
// frags reg-cached: 8 B-frag + 2x8 A-frag ds_read_b128 per tile (minimal 24).
// Same involution bank swizzle: LDS[r][pc] holds logical chunk pc^(r&7);
// stage source col = ((l&7)^((l>>3)&7))*8; read pc = (kh*4+lq)^(lm&7)
// -> 2 lanes/bank-group, conflict-free. kh-outer MFMA order spaces the two
// writes to each acc 15 MFMAs apart. Only FC uses this (M=8192 N=3072 ->
// 384 blocks; QKV 288 / Wo,proj 96 blocks lose to 1-blk/CU makespan).
template <int EPI>
__global__ __launch_bounds__(512, 1) void gemm256_k(const ushort_t* __restrict__ A,
                                                    const ushort_t* __restrict__ Bt,
                                                    void* __restrict__ outp,
                                                    int N, int K) {
  __shared__ __align__(16) ushort_t As[2][256][64];
  __shared__ __align__(16) ushort_t Bs[2][256][64];
  int t = threadIdx.x;
  int lane = t & 63, w = t >> 6;

  int nwg = (int)(gridDim.x * gridDim.y);
  int orig = (int)(blockIdx.y * gridDim.x + blockIdx.x);
  int swz = (nwg & 7) ? orig : ((orig & 7) * (nwg >> 3) + (orig >> 3));
  int bx = swz % (int)gridDim.x, by = swz / (int)gridDim.x;
  int bn = bx * 256, bm = by * 256;

  int wm = (w >> 2) * 128, wn = (w & 3) * 64;
  int lm = lane & 15, lq = lane >> 4;
  int rswz = lm & 7;

  // staging: wave w covers rows [w*32, w*32+32) of both tiles, 4 insts x 8 rows
  int srow = w * 32 + (lane >> 3);
  int scol = (((lane & 7) ^ ((lane >> 3) & 7)) << 3);
  const ushort_t* gaS = A  + (size_t)(bm + srow) * K + scol;
  const ushort_t* gbS = Bt + (size_t)(bn + srow) * K + scol;

  f32x4 acc[8][4];
#pragma unroll
  for (int m = 0; m < 8; m++)
#pragma unroll
    for (int n = 0; n < 4; n++) acc[m][n] = {0.f, 0.f, 0.f, 0.f};

#define STAGE256(BUF, TILE) do {                                          \
    int k0_ = (TILE) * 64;                                                \
    _Pragma("unroll") for (int i = 0; i < 4; i++) {                       \
      gload_lds16(gaS + (size_t)(8 * i) * K + k0_, &As[BUF][w * 32 + 8 * i][0]); \
      gload_lds16(gbS + (size_t)(8 * i) * K + k0_, &Bs[BUF][w * 32 + 8 * i][0]); \
    }                                                                     \
  } while (0)

  int NT = K >> 6;                       // K=768 -> 12 tiles
  STAGE256(0, 0);
  for (int tt = 0; tt < NT; tt++) {
    int cb = tt & 1;
    if (tt + 1 < NT) {
      STAGE256(cb ^ 1, tt + 1);
      asm volatile("s_waitcnt vmcnt(8)" ::: "memory");   // tile tt landed; tt+1 in flight
    } else {
      asm volatile("s_waitcnt vmcnt(0)" ::: "memory");   // tail: drain
    }
    __builtin_amdgcn_s_barrier();
    asm volatile("" ::: "memory");
    {
      const ushort_t* Ab = &As[cb][0][0];
      const ushort_t* Bb = &Bs[cb][0][0];
      bf16x8_t bg[4][2];
#pragma unroll
      for (int n = 0; n < 4; n++)
#pragma unroll
        for (int kh = 0; kh < 2; kh++) {
          int r = wn + n * 16 + lm;
          int pc = (kh * 4 + lq) ^ rswz;
          bg[n][kh] = *(const bf16x8_t*)(Bb + r * 64 + pc * 8);
        }
      bf16x8_t af[4][2];
      // m-half 0 (rows wm .. wm+63)
#pragma unroll
      for (int m = 0; m < 4; m++)
#pragma unroll
        for (int kh = 0; kh < 2; kh++) {
          int r = wm + m * 16 + lm;
          int pc = (kh * 4 + lq) ^ rswz;
          af[m][kh] = *(const bf16x8_t*)(Ab + r * 64 + pc * 8);
        }
      __builtin_amdgcn_s_setprio(1);
#pragma unroll
      for (int kh = 0; kh < 2; kh++)
#pragma unroll
        for (int m = 0; m < 4; m++)
#pragma unroll
          for (int n = 0; n < 4; n++)
            MFMA16(acc[m][n], af[m][kh], bg[n][kh]);
      __builtin_amdgcn_s_setprio(0);
      // m-half 1 (rows wm+64 .. wm+127)
#pragma unroll
      for (int m = 0; m < 4; m++)
#pragma unroll
        for (int kh = 0; kh < 2; kh++) {
          int r = wm + 64 + m * 16 + lm;
          int pc = (kh * 4 + lq) ^ rswz;
          af[m][kh] = *(const bf16x8_t*)(Ab + r * 64 + pc * 8);
        }
      __builtin_amdgcn_s_setprio(1);
#pragma unroll
      for (int kh = 0; kh < 2; kh++)
#pragma unroll
        for (int m = 0; m < 4; m++)
#pragma unroll
          for (int n = 0; n < 4; n++)
            MFMA16(acc[m + 4][n], af[m][kh], bg[n][kh]);
      __builtin_amdgcn_s_setprio(0);
    }
    asm volatile("" ::: "memory");
    __builtin_amdgcn_s_barrier();        // all reads of buf cb done -> refillable
  }
#undef STAGE256

#pragma unroll
  for (int m = 0; m < 8; m++) {
    int row0 = bm + wm + m * 16 + lq * 4;
#pragma unroll
    for (int n = 0; n < 4; n++) {
      int col = bn + wn + n * 16 + lm;
#pragma unroll
      for (int r = 0; r < 4; r++) {
        float v = acc[m][n][r];
        size_t idx = (size_t)(row0 + r) * N + col;
        if constexpr (EPI == 0) ((ushort_t*)outp)[idx] = f2bf(v);
        else                    ((ushort_t*)outp)[idx] = f2bf(gelu_f(v));
      }
    }
  }
}

// ---------------- flash attention (causal) ----------------
__device__ __forceinline__ void stage64(const ushort_t* __restrict__ g, size_t strideE,
                                        ushort_t* l, int w, int lane) {
  int rl = lane >> 3;                        // local row 0..7 within 8-row slab
  int ce = ((lane & 7) ^ rl) << 3;           // pre-swizzled element col (8-elem chunks)
  const ushort_t* g0 = g + (size_t)(w * 16 + rl) * strideE + ce;
  gload_lds16(g0, l + (size_t)(w * 16) * 64);
  const ushort_t* g1 = g + (size_t)(w * 16 + 8 + rl) * strideE + ce;
  gload_lds16(g1, l + (size_t)(w * 16 + 8) * 64);
}

__global__ __launch_bounds__(256, 3) void attn_k(const ushort_t* __restrict__ qkv,
                                                 const ushort_t* __restrict__ vg,
                                                 ushort_t* __restrict__ y) {
  __shared__ __align__(16) ushort_t Ks[2][64][64];   // [buf][t_local][d] swizzled
  __shared__ __align__(16) ushort_t Vs[2][64][64];   // [buf][d][t_local] swizzled
  __shared__ __align__(16) ushort_t Ps[4][16][72];

  int t = threadIdx.x;
  int w = t >> 6, lane = t & 63;
  int lm = lane & 15, qq = lane >> 4, q8 = qq * 8;
  int bh = blockIdx.x;
  int qt = (int)gridDim.y - 1 - (int)blockIdx.y;   // heavy q-tiles dispatch first
  int b = bh / H_, h = bh % H_;

  size_t baserow = (size_t)b * T_;
  const ushort_t* qkvb = qkv + baserow * C3_ + h * D_;
  const ushort_t* kbase = qkvb + C_;
  const ushort_t* vbase = vg + (size_t)bh * D_ * T_;

  int qrow0 = qt * 64 + w * 16;   // this wave's 16 q rows
  const ushort_t* qp = qkvb + (size_t)(qrow0 + lm) * C3_ + q8;
  bf16x8_t aq0 = *(const bf16x8_t*)(qp);
  bf16x8_t aq1 = *(const bf16x8_t*)(qp + 32);
  __builtin_amdgcn_s_waitcnt(0);   // drain Q loads so in-loop vmcnt counting is exact

  const f32x4 fz = {0.f, 0.f, 0.f, 0.f};
  f32x4 aO0 = fz, aO1 = fz, aO2 = fz, aO3 = fz;
  f32x4 lsum = fz;                 // per-lane partial softmax denominators

  const float SC = 0.125f * 1.44269504088896340736f;  // scale * log2(e)

#define BODY(CUR, KT, MASKED)                                                   \
  {                                                                             \
    const char* Kb = (const char*)&Ks[CUR][0][0];                               \
    const char* Vb = (const char*)&Vs[CUR][0][0];                               \
    const int rsw = (lm & 7) << 4;                                              \
    const int c0 = (qq * 16) ^ rsw;                                             \
    const int c1 = (64 + qq * 16) ^ rsw;                                        \
    bf16x8_t kf[8], vv[8];                                                      \
    _Pragma("unroll") for (int j = 0; j < 4; j++) {                             \
      int rb = (j * 16 + lm) << 7;                                              \
      kf[2*j]   = *(const bf16x8_t*)(Kb + rb + c0);                             \
      kf[2*j+1] = *(const bf16x8_t*)(Kb + rb + c1);                             \
      vv[2*j]   = *(const bf16x8_t*)(Vb + rb + c0);                             \
      vv[2*j+1] = *(const bf16x8_t*)(Vb + rb + c1);                             \
    }                                                                           \
    f32x4 sa0 = fz, sa1 = fz, sa2 = fz, sa3 = fz;                               \
    MFMA16(sa0, aq0, kf[0]); MFMA16(sa0, aq1, kf[1]);                           \
    MFMA16(sa1, aq0, kf[2]); MFMA16(sa1, aq1, kf[3]);                           \
    MFMA16(sa2, aq0, kf[4]); MFMA16(sa2, aq1, kf[5]);                           \
    MFMA16(sa3, aq0, kf[6]); MFMA16(sa3, aq1, kf[7]);                           \
    _Pragma("unroll") for (int j = 0; j < 4; j++) {                             \
      f32x4 sj = (j == 0) ? sa0 : (j == 1) ? sa1 : (j == 2) ? sa2 : sa3;        \
      _Pragma("unroll") for (int r2 = 0; r2 < 4; r2++) {                        \
        float v = sj[r2] * SC;                                                  \
        if (MASKED && (j * 16 + lm) > (w * 16 + qq * 4 + r2)) v = -1e30f;       \
        float p = exp2f(v);                                                     \
        lsum[r2] += p;                                                          \
        Ps[w][qq * 4 + r2][j * 16 + lm] = f2bf_trunc(p);                        \
      }                                                                         \
    }                                                                           \
    {                                                                           \
      bf16x8_t ap_lo = *(const bf16x8_t*)&Ps[w][lm][q8];                        \
      bf16x8_t ap_hi = *(const bf16x8_t*)&Ps[w][lm][32 + q8];                   \
      MFMA16(aO0, ap_lo, vv[0]); MFMA16(aO0, ap_hi, vv[1]);                     \
      MFMA16(aO1, ap_lo, vv[2]); MFMA16(aO1, ap_hi, vv[3]);                     \
      MFMA16(aO2, ap_lo, vv[4]); MFMA16(aO2, ap_hi, vv[5]);                     \
      MFMA16(aO3, ap_lo, vv[6]); MFMA16(aO3, ap_hi, vv[7]);                     \
    }                                                                           \
  }

  // prologue: stage tile 0 into buffer 0 (4 async loads per wave)
  stage64(kbase, C3_, &Ks[0][0][0], w, lane);
  stage64(vbase, T_, &Vs[0][0][0], w, lane);
  int cur = 0;
  for (int kt = 0; kt <= qt; ++kt) {
    if (kt < qt) {
      stage64(kbase + (size_t)(kt + 1) * 64 * C3_, C3_, &Ks[cur ^ 1][0][0], w, lane);
      stage64(vbase + (size_t)(kt + 1) * 64,       T_,  &Vs[cur ^ 1][0][0], w, lane);
      asm volatile("s_waitcnt vmcnt(4)" ::: "memory");  // tile kt landed; kt+1 in flight
    } else {
      asm volatile("s_waitcnt vmcnt(0)" ::: "memory");  // last tile: drain
    }
    __builtin_amdgcn_s_barrier();      // all waves' tile-kt data visible
    asm volatile("" ::: "memory");
    if (kt == qt) { BODY(cur, kt, true) }
    else          { BODY(cur, kt, false) }
    asm volatile("" ::: "memory");
    __builtin_amdgcn_s_barrier();      // safe to overwrite buffer cur next iter
    cur ^= 1;
  }
#undef BODY

#pragma unroll
  for (int r2 = 0; r2 < 4; r2++) {
    float s = lsum[r2];
    s += __shfl_xor(s, 1);
    s += __shfl_xor(s, 2);
    s += __shfl_xor(s, 4);
    s += __shfl_xor(s, 8);
    float inv = 1.f / s;
    size_t orow = (baserow + qrow0 + qq * 4 + r2) * C_ + h * D_;
    y[orow + lm]      = f2bf(aO0[r2] * inv);
    y[orow + 16 + lm] = f2bf(aO1[r2] * inv);
    y[orow + 32 + lm] = f2bf(aO2[r2] * inv);
    y[orow + 48 + lm] = f2bf(aO3[r2] * inv);
  }
}

extern "C" void kernel_launch(void* const* d_in, const int* in_sizes, int n_in,
                              void* d_out, int out_size, void* d_ws, size_t ws_size,
                              hipStream_t stream) {
  (void)in_sizes; (void)n_in; (void)out_size; (void)ws_size;
  const float* x      = (const float*)d_in[0];
  const float* ln1_g  = (const float*)d_in[1];
  const float* ln1_b  = (const float*)d_in[2];
  const float* W_attn = (const float*)d_in[3];
  const float* W_o    = (const float*)d_in[4];
  const float* ln2_g  = (const float*)d_in[5];
  const float* ln2_b  = (const float*)d_in[6];
  const float* W_fc   = (const float*)d_in[7];
  const float* W_proj = (const float*)d_in[8];

  char* ws = (char*)d_ws;
  ushort_t* big  = (ushort_t*)(ws);
  ushort_t* Vg   = (ushort_t*)(ws + 37748736);  // V^T [48][64][2048] bf16; dead before h is written
  ushort_t* tmp  = (ushort_t*)(ws + 50331648);  // xhat1 / y / xhat2 (8192x768 bf16)
  float*    x2   = (float*)   (ws + 62914560);  // residual1 fp32 (8192x768)
  ushort_t* Wat  = (ushort_t*)(ws + 88080384);  // W_attn^T [2304,768] bf16
  ushort_t* Wot  = (ushort_t*)(ws + 91619328);  // W_o^T    [768,768]  bf16
  ushort_t* Wfct = (ushort_t*)(ws + 92798976);  // W_fc^T   [3072,768] bf16
  ushort_t* Wpt  = (ushort_t*)(ws + 97517568);  // W_proj^T [768,3072] bf16

  dim3 tb(32, 8);
  transpose_k<<<dim3(C3_ / 32, C_ / 32), tb, 0, stream>>>(W_attn, Wat, C_, C3_);
  transpose_k<<<dim3(C_ / 32, C_ / 32), tb, 0, stream>>>(W_o, Wot, C_, C_);
  transpose_k<<<dim3(HID_ / 32, C_ / 32), tb, 0, stream>>>(W_fc, Wfct, C_, HID_);
  transpose_k<<<dim3(C_ / 32, HID_ / 32), tb, 0, stream>>>(W_proj, Wpt, HID_, C_);

  ln_k<<<M_, 256, 0, stream>>>(x, ln1_g, ln1_b, tmp);
  gemm_bt_k<0><<<dim3(C3_ / 128, M_ / 128), 256, 0, stream>>>(tmp, Wat, nullptr, big, C3_, C_);
  vtrans_k<<<dim3(T_ / 32, D_ / 32, B_ * H_), tb, 0, stream>>>(big, Vg);
  attn_k<<<dim3(B_ * H_, T_ / 64), 256, 0, stream>>>(big, Vg, tmp);
  gemm_bt_k<1><<<dim3(C_ / 128, M_ / 128), 256, 0, stream>>>(tmp, Wot, x, x2, C_, C_);
  ln_k<<<M_, 256, 0, stream>>>(x2, ln2_g, ln2_b, tmp);
  gemm256_k<2><<<dim3(HID_ / 256, M_ / 256), 512, 0, stream>>>(tmp, Wfct, big, HID_, C_);
  gemm_bt_k<1><<<dim3(C_ / 128, M_ / 128), 256, 0, stream>>>(big, Wpt, x2, d_out, C_, HID_);
}